// Round 3
// baseline (922.875 us; speedup 1.0000x reference)
//
#include <hip/hip_runtime.h>

// LSTM recurrence, 50 steps. B=2048, T=50, F=256, H=256, gates i,f,g,o.
// Phase 0: pack W,U (fp32) -> bf16 in MFMA-fragment order (W2, U2).
// Phase 1: xz = x@W + b for ALL timesteps (parallel GEMM), stored bf16 in
//          per-thread fragment layout (coalesced dwordx2 in phase 2).
// Phase 2: ONE persistent kernel, 64 blocks x 32 batch rows x all 1024
//          z-cols. No grid sync (batch rows independent). h in swizzled LDS,
//          c in registers. U: kf0 reg-resident, kf1-2 LDS-resident (128KB),
//          kf3-7 streamed from L2 (frag-packed, coalesced) each step.

#define B_ 2048
#define T_ 50
#define F_ 256
#define H_ 256
#define NZ 1024      // 4H

typedef __attribute__((ext_vector_type(8))) short short8;
typedef __attribute__((ext_vector_type(4))) float f32x4;
typedef unsigned short ushort_t;
typedef unsigned int uint_t;

__device__ __forceinline__ ushort_t f2bf(float f) {
    uint_t u = __float_as_uint(f);
    return (ushort_t)((u + 0x7FFFu + ((u >> 16) & 1u)) >> 16);
}
__device__ __forceinline__ uint_t pack2bf(float lo, float hi) {
    return (uint_t)f2bf(lo) | ((uint_t)f2bf(hi) << 16);
}
__device__ __forceinline__ float bf2f(ushort_t u) {
    return __uint_as_float(((uint_t)u) << 16);
}
__device__ __forceinline__ float sigm(float z) {
    return __builtin_amdgcn_rcpf(1.0f + __builtin_amdgcn_exp2f(z * -1.44269504f));
}
__device__ __forceinline__ float tanh_f(float z) {
    return 2.0f * __builtin_amdgcn_rcpf(1.0f + __builtin_amdgcn_exp2f(z * -2.88539008f)) - 1.0f;
}
__device__ __forceinline__ float xz_at(uint2 u, int j) {
    uint_t v = (j < 2) ? u.x : u.y;
    v = (j & 1) ? (v >> 16) : (v & 0xFFFFu);
    return bf2f((ushort_t)v);
}

// -------- pack: fp32 [256][1024] -> bf16 frag-order panels ----------------
// dst idx (ushorts): (((kf*8 + w)*8 + nf)*64 + lane)*8 + e
// value = src[kf*32 + (lane>>4)*8 + e][(nf>>1)*256 + w*32 + (nf&1)*16 + (lane&15)]
__global__ void pack_wu(const float* __restrict__ Wm, const float* __restrict__ Um,
                        ushort_t* __restrict__ W2, ushort_t* __restrict__ U2) {
    int gid  = blockIdx.x * 256 + threadIdx.x;   // 65536 total
    int lane = gid & 63;
    int nf   = (gid >> 6) & 7;
    int w    = (gid >> 9) & 7;
    int kf   = (gid >> 12) & 7;
    int mat  = gid >> 15;
    const float* src = mat ? Um : Wm;
    ushort_t* dst    = mat ? U2 : W2;
    int col = (nf >> 1) * 256 + w * 32 + (nf & 1) * 16 + (lane & 15);
    int kb  = kf * 32 + (lane >> 4) * 8;
    short8 v;
#pragma unroll
    for (int e = 0; e < 8; ++e)
        v[e] = (short)f2bf(src[(size_t)(kb + e) * NZ + col]);
    *(short8*)(dst + ((((size_t)kf * 8 + w) * 8 + nf) * 64 + lane) * 8) = v;
}

// -------- phase 1: xz[t] = x[:,t,:] @ W + b  (bf16, frag layout) ----------
__global__ __launch_bounds__(512, 2) void xw_gemm(
    const float* __restrict__ x, const float* __restrict__ bias,
    const ushort_t* __restrict__ W2, ushort_t* __restrict__ xz2) {
    __shared__ __align__(16) ushort_t As[32 * 256];   // 16 KB, swizzled

    const int tid = threadIdx.x;
    const int t = blockIdx.x, rb = blockIdx.y, row0 = rb * 32;
    const int w = tid >> 6, lane = tid & 63, r16 = lane & 15, q = lane >> 4;

    // stage A: 32 rows x 256 k, fp32->bf16, chunk-XOR swizzle
    {
        int sr = tid >> 4, sc = tid & 15;
        const float* xp = x + ((size_t)(row0 + sr) * T_ + t) * F_ + sc * 16;
        float4 f0 = *(const float4*)(xp + 0);
        float4 f1 = *(const float4*)(xp + 4);
        float4 f2 = *(const float4*)(xp + 8);
        float4 f3 = *(const float4*)(xp + 12);
        uint4 u0 = {pack2bf(f0.x, f0.y), pack2bf(f0.z, f0.w),
                    pack2bf(f1.x, f1.y), pack2bf(f1.z, f1.w)};
        uint4 u1 = {pack2bf(f2.x, f2.y), pack2bf(f2.z, f2.w),
                    pack2bf(f3.x, f3.y), pack2bf(f3.z, f3.w)};
        int c0 = (2 * sc) ^ (sr & 7), c1 = (2 * sc + 1) ^ (sr & 7);
        *(uint4*)&As[sr * 256 + c0 * 8] = u0;
        *(uint4*)&As[sr * 256 + c1 * 8] = u1;
    }
    float bcol[8];
#pragma unroll
    for (int nf = 0; nf < 8; ++nf)
        bcol[nf] = bias[(nf >> 1) * 256 + w * 32 + (nf & 1) * 16 + r16];
    __syncthreads();

    f32x4 acc0[8], acc1[8];
#pragma unroll
    for (int nf = 0; nf < 8; ++nf) {
        acc0[nf] = (f32x4){0.f, 0.f, 0.f, 0.f};
        acc1[nf] = (f32x4){0.f, 0.f, 0.f, 0.f};
    }
    short8 SB0[8], SB1[8];

#define LOADB(BUF, KF_)                                                       \
    _Pragma("unroll") for (int nf = 0; nf < 8; ++nf)                          \
        BUF[nf] = *(const short8*)(W2 +                                       \
            ((((size_t)(KF_) * 8 + w) * 8 + nf) * 64 + lane) * 8);

#define MF1(BUF, KF_)                                                         \
    do {                                                                      \
        short8 a0_ = *(const short8*)&As[r16 * 256 + (((KF_)*4 + q) ^ (r16 & 7)) * 8];       \
        short8 a1_ = *(const short8*)&As[(16 + r16) * 256 + (((KF_)*4 + q) ^ (r16 & 7)) * 8];\
        _Pragma("unroll") for (int nf = 0; nf < 8; ++nf) {                    \
            acc0[nf] = __builtin_amdgcn_mfma_f32_16x16x32_bf16(a0_, BUF[nf], acc0[nf], 0, 0, 0); \
            acc1[nf] = __builtin_amdgcn_mfma_f32_16x16x32_bf16(a1_, BUF[nf], acc1[nf], 0, 0, 0); \
        }                                                                     \
    } while (0)

    LOADB(SB0, 0); LOADB(SB1, 1);
    MF1(SB0, 0); LOADB(SB0, 2);
    MF1(SB1, 1); LOADB(SB1, 3);
    MF1(SB0, 2); LOADB(SB0, 4);
    MF1(SB1, 3); LOADB(SB1, 5);
    MF1(SB0, 4); LOADB(SB0, 6);
    MF1(SB1, 5); LOADB(SB1, 7);
    MF1(SB0, 6);
    MF1(SB1, 7);

    // epilogue: + bias, pack bf16, store coalesced in frag layout
    uint2* outp = (uint2*)xz2;
    const size_t cb = (((size_t)t * 64 + rb) * 8 + w) * 16;
#pragma unroll
    for (int m = 0; m < 2; ++m) {
#pragma unroll
        for (int nf = 0; nf < 8; ++nf) {
            f32x4 a = m ? acc1[nf] : acc0[nf];
            float b = bcol[nf];
            uint2 o = {pack2bf(a[0] + b, a[1] + b), pack2bf(a[2] + b, a[3] + b)};
            outp[(cb + m * 8 + nf) * 64 + lane] = o;
        }
    }
#undef LOADB
#undef MF1
}

// -------- phase 2: persistent recurrence --------------------------------
__global__ __launch_bounds__(512, 2) void lstm_rec(
    const ushort_t* __restrict__ U2, const ushort_t* __restrict__ xz2,
    float* __restrict__ outp) {
    __shared__ __align__(16) ushort_t BL[65536];    // U kf1,kf2 (128 KB)
    __shared__ __align__(16) ushort_t hb[32 * 256]; // h, swizzled (16 KB)

    const int tid = threadIdx.x;
    const int rb = blockIdx.x, row0 = rb * 32;
    const int w = tid >> 6, lane = tid & 63, r16 = lane & 15, q = lane >> 4;

    // LDS-resident kf1..kf2: linear 128 KB copy from U2 (+64 KB offset)
    {
        const char* srcb = (const char*)U2 + 65536;
#pragma unroll
        for (int i = 0; i < 16; ++i) {
            int off = i * 8192 + tid * 16;
            __builtin_amdgcn_global_load_lds(
                (const __attribute__((address_space(1))) void*)(srcb + off),
                (__attribute__((address_space(3))) void*)((char*)BL + off),
                16, 0, 0);
        }
    }
    // h0 = 0
    *(uint4*)&hb[tid * 16] = (uint4){0, 0, 0, 0};
    *(uint4*)&hb[tid * 16 + 8] = (uint4){0, 0, 0, 0};

    // register-resident kf0
    short8 BR[8];
#pragma unroll
    for (int nf = 0; nf < 8; ++nf)
        BR[nf] = *(const short8*)(U2 + (((size_t)w * 8 + nf) * 64 + lane) * 8);

#define LOADU(BUF, KF_)                                                       \
    _Pragma("unroll") for (int nf = 0; nf < 8; ++nf)                          \
        BUF[nf] = *(const short8*)(U2 +                                       \
            ((((size_t)(KF_) * 8 + w) * 8 + nf) * 64 + lane) * 8);

#define AFRAG(KF_, M_)                                                        \
    (*(const short8*)&hb[((M_)*16 + r16) * 256 + (((KF_)*4 + q) ^ (r16 & 7)) * 8])

#define MFKF(BUF, KF_)                                                        \
    do {                                                                      \
        short8 a0_ = AFRAG(KF_, 0);                                           \
        short8 a1_ = AFRAG(KF_, 1);                                           \
        _Pragma("unroll") for (int nf = 0; nf < 8; ++nf) {                    \
            acc[nf] = __builtin_amdgcn_mfma_f32_16x16x32_bf16(a0_, BUF[nf], acc[nf], 0, 0, 0);     \
            acc[8 + nf] = __builtin_amdgcn_mfma_f32_16x16x32_bf16(a1_, BUF[nf], acc[8 + nf], 0, 0, 0); \
        }                                                                     \
    } while (0)

    short8 SB0[8], SB1[8];
    LOADU(SB0, 3); LOADU(SB1, 4);     // for t=0

    f32x4 acc[16];
    f32x4 creg[4];
#pragma unroll
    for (int k = 0; k < 4; ++k) creg[k] = (f32x4){0.f, 0.f, 0.f, 0.f};
    uint2 XZ[16];
    const uint2* xzp = (const uint2*)xz2;

    __syncthreads();   // BL + hb ready

    for (int t = 0; t < T_; ++t) {
        // xz fragment loads for THIS step: issued early, hidden under MFMAs
        const size_t cb = (((size_t)t * 64 + rb) * 8 + w) * 16;
#pragma unroll
        for (int k = 0; k < 16; ++k) XZ[k] = xzp[(cb + k) * 64 + lane];

#pragma unroll
        for (int k = 0; k < 16; ++k) acc[k] = (f32x4){0.f, 0.f, 0.f, 0.f};

        MFKF(BR, 0);                        // kf0 registers
#pragma unroll
        for (int sel = 0; sel < 2; ++sel) { // kf1,kf2 from LDS
            short8 a0_ = AFRAG(1 + sel, 0);
            short8 a1_ = AFRAG(1 + sel, 1);
#pragma unroll
            for (int nf = 0; nf < 8; ++nf) {
                short8 b_ = *(const short8*)&BL[(((sel * 8 + w) * 8) + nf) * 512 + lane * 8];
                acc[nf] = __builtin_amdgcn_mfma_f32_16x16x32_bf16(a0_, b_, acc[nf], 0, 0, 0);
                acc[8 + nf] = __builtin_amdgcn_mfma_f32_16x16x32_bf16(a1_, b_, acc[8 + nf], 0, 0, 0);
            }
        }
        MFKF(SB0, 3); LOADU(SB0, 5);        // kf3-7 streamed (L2-hot)
        MFKF(SB1, 4); LOADU(SB1, 6);
        MFKF(SB0, 5); LOADU(SB0, 7);
        MFKF(SB1, 6);
        MFKF(SB0, 7);

        __syncthreads();                    // all h reads done

        LOADU(SB0, 3); LOADU(SB1, 4);       // next step's kf3/kf4: fly during epilogue

        // epilogue: gates, cell update, h -> swizzled LDS
#pragma unroll
        for (int m = 0; m < 2; ++m) {
#pragma unroll
            for (int hf = 0; hf < 2; ++hf) {
#pragma unroll
                for (int j = 0; j < 4; ++j) {
                    float zi = acc[m * 8 + (0 + hf)][j] + xz_at(XZ[m * 8 + 0 + hf], j);
                    float zf = acc[m * 8 + (2 + hf)][j] + xz_at(XZ[m * 8 + 2 + hf], j);
                    float zg = acc[m * 8 + (4 + hf)][j] + xz_at(XZ[m * 8 + 4 + hf], j);
                    float zo = acc[m * 8 + (6 + hf)][j] + xz_at(XZ[m * 8 + 6 + hf], j);
                    float ig = sigm(zi);
                    float fg = sigm(zf);
                    float gg = tanh_f(zg);
                    float og = sigm(zo);
                    float cn = fg * creg[m * 2 + hf][j] + ig * gg;
                    float hn = og * tanh_f(cn);
                    creg[m * 2 + hf][j] = cn;
                    int row = m * 16 + q * 4 + j;
                    int hcol = w * 32 + hf * 16 + r16;
                    int chunk = (hcol >> 3) ^ (row & 7);
                    hb[row * 256 + chunk * 8 + (hcol & 7)] = f2bf(hn);
                    if (t == T_ - 1) {
                        size_t oi = (size_t)(row0 + row) * H_ + hcol;
                        outp[oi] = hn;
                        outp[(size_t)B_ * H_ + oi] = cn;
                    }
                }
            }
        }
        __syncthreads();                    // h visible for next step
    }
#undef LOADU
#undef AFRAG
#undef MFKF
}

extern "C" void kernel_launch(void* const* d_in, const int* in_sizes, int n_in,
                              void* d_out, int out_size, void* d_ws, size_t ws_size,
                              hipStream_t stream) {
    const float* x    = (const float*)d_in[0];
    const float* Wm   = (const float*)d_in[1];
    const float* Um   = (const float*)d_in[2];
    const float* bias = (const float*)d_in[3];

    // ws: W2 (512 KB) | U2 (512 KB) | xz2 (210 MB)   (ws_size = 400 MiB)
    ushort_t* W2  = (ushort_t*)d_ws;
    ushort_t* U2  = W2 + 262144;
    ushort_t* xz2 = U2 + 262144;

    pack_wu<<<256, 256, 0, stream>>>(Wm, Um, W2, U2);
    dim3 g1(T_, 64);
    xw_gemm<<<g1, 512, 0, stream>>>(x, bias, W2, xz2);
    lstm_rec<<<64, 512, 0, stream>>>(U2, xz2, (float*)d_out);
}

// Round 4
// 413.363 us; speedup vs baseline: 2.2326x; 2.2326x over previous
//
#include <hip/hip_runtime.h>

// LSTM recurrence, 50 steps. B=2048, T=50, F=256, H=256, gates i,f,g,o.
// Phase 0: pack W,U (fp32) -> bf16 in MFMA-fragment order (W2, U2).
// Phase 1: xz = x@W + b for ALL timesteps (parallel GEMM), bf16 frag layout.
// Phase 2: ONE persistent kernel, 128 blocks x 16 batch rows x all 1024
//          z-cols. h in swizzled LDS, c in registers. U: kf0-2 in registers,
//          kf3-4 LDS-resident, kf5-7 streamed from L2 per step (reg dbuf).
//          t-loop unroll DISABLED (runtime T arg) -- round-3's 18us/step was
//          consistent with full-unroll I-cache thrash (~400KB body vs 32KB L1I).

#define B_ 2048
#define T_ 50
#define F_ 256
#define H_ 256
#define NZ 1024      // 4H

typedef __attribute__((ext_vector_type(8))) short short8;
typedef __attribute__((ext_vector_type(4))) float f32x4;
typedef unsigned short ushort_t;
typedef unsigned int uint_t;

__device__ __forceinline__ ushort_t f2bf(float f) {
    uint_t u = __float_as_uint(f);
    return (ushort_t)((u + 0x7FFFu + ((u >> 16) & 1u)) >> 16);
}
__device__ __forceinline__ uint_t pack2bf(float lo, float hi) {
    return (uint_t)f2bf(lo) | ((uint_t)f2bf(hi) << 16);
}
__device__ __forceinline__ float bf2f(ushort_t u) {
    return __uint_as_float(((uint_t)u) << 16);
}
__device__ __forceinline__ float sigm(float z) {
    return __builtin_amdgcn_rcpf(1.0f + __builtin_amdgcn_exp2f(z * -1.44269504f));
}
__device__ __forceinline__ float tanh_f(float z) {
    return 2.0f * __builtin_amdgcn_rcpf(1.0f + __builtin_amdgcn_exp2f(z * -2.88539008f)) - 1.0f;
}
__device__ __forceinline__ float xz_at(uint2 u, int j) {
    uint_t v = (j < 2) ? u.x : u.y;
    v = (j & 1) ? (v >> 16) : (v & 0xFFFFu);
    return bf2f((ushort_t)v);
}

// -------- pack: fp32 [256][1024] -> bf16 frag-order panels ----------------
// dst idx (ushorts): (((kf*8 + w)*8 + nf)*64 + lane)*8 + e
// value = src[kf*32 + (lane>>4)*8 + e][(nf>>1)*256 + w*32 + (nf&1)*16 + (lane&15)]
__global__ void pack_wu(const float* __restrict__ Wm, const float* __restrict__ Um,
                        ushort_t* __restrict__ W2, ushort_t* __restrict__ U2) {
    int gid  = blockIdx.x * 256 + threadIdx.x;   // 65536 total
    int lane = gid & 63;
    int nf   = (gid >> 6) & 7;
    int w    = (gid >> 9) & 7;
    int kf   = (gid >> 12) & 7;
    int mat  = gid >> 15;
    const float* src = mat ? Um : Wm;
    ushort_t* dst    = mat ? U2 : W2;
    int col = (nf >> 1) * 256 + w * 32 + (nf & 1) * 16 + (lane & 15);
    int kb  = kf * 32 + (lane >> 4) * 8;
    short8 v;
#pragma unroll
    for (int e = 0; e < 8; ++e)
        v[e] = (short)f2bf(src[(size_t)(kb + e) * NZ + col]);
    *(short8*)(dst + ((((size_t)kf * 8 + w) * 8 + nf) * 64 + lane) * 8) = v;
}

// -------- phase 1: xz[t] = x[:,t,:] @ W + b  (bf16, frag layout) ----------
__global__ __launch_bounds__(512, 2) void xw_gemm(
    const float* __restrict__ x, const float* __restrict__ bias,
    const ushort_t* __restrict__ W2, ushort_t* __restrict__ xz2) {
    __shared__ __align__(16) ushort_t As[32 * 256];   // 16 KB, swizzled

    const int tid = threadIdx.x;
    const int t = blockIdx.x, rb = blockIdx.y, row0 = rb * 32;
    const int w = tid >> 6, lane = tid & 63, r16 = lane & 15, q = lane >> 4;

    // stage A: 32 rows x 256 k, fp32->bf16, chunk-XOR swizzle
    {
        int sr = tid >> 4, sc = tid & 15;
        const float* xp = x + ((size_t)(row0 + sr) * T_ + t) * F_ + sc * 16;
        float4 f0 = *(const float4*)(xp + 0);
        float4 f1 = *(const float4*)(xp + 4);
        float4 f2 = *(const float4*)(xp + 8);
        float4 f3 = *(const float4*)(xp + 12);
        uint4 u0 = {pack2bf(f0.x, f0.y), pack2bf(f0.z, f0.w),
                    pack2bf(f1.x, f1.y), pack2bf(f1.z, f1.w)};
        uint4 u1 = {pack2bf(f2.x, f2.y), pack2bf(f2.z, f2.w),
                    pack2bf(f3.x, f3.y), pack2bf(f3.z, f3.w)};
        int c0 = (2 * sc) ^ (sr & 7), c1 = (2 * sc + 1) ^ (sr & 7);
        *(uint4*)&As[sr * 256 + c0 * 8] = u0;
        *(uint4*)&As[sr * 256 + c1 * 8] = u1;
    }
    float bcol[8];
#pragma unroll
    for (int nf = 0; nf < 8; ++nf)
        bcol[nf] = bias[(nf >> 1) * 256 + w * 32 + (nf & 1) * 16 + r16];
    __syncthreads();

    f32x4 acc0[8], acc1[8];
#pragma unroll
    for (int nf = 0; nf < 8; ++nf) {
        acc0[nf] = (f32x4){0.f, 0.f, 0.f, 0.f};
        acc1[nf] = (f32x4){0.f, 0.f, 0.f, 0.f};
    }
    short8 SB0[8], SB1[8];

#define LOADB(BUF, KF_)                                                       \
    _Pragma("unroll") for (int nf = 0; nf < 8; ++nf)                          \
        BUF[nf] = *(const short8*)(W2 +                                       \
            ((((size_t)(KF_) * 8 + w) * 8 + nf) * 64 + lane) * 8);

#define MF1(BUF, KF_)                                                         \
    do {                                                                      \
        short8 a0_ = *(const short8*)&As[r16 * 256 + (((KF_)*4 + q) ^ (r16 & 7)) * 8];       \
        short8 a1_ = *(const short8*)&As[(16 + r16) * 256 + (((KF_)*4 + q) ^ (r16 & 7)) * 8];\
        _Pragma("unroll") for (int nf = 0; nf < 8; ++nf) {                    \
            acc0[nf] = __builtin_amdgcn_mfma_f32_16x16x32_bf16(a0_, BUF[nf], acc0[nf], 0, 0, 0); \
            acc1[nf] = __builtin_amdgcn_mfma_f32_16x16x32_bf16(a1_, BUF[nf], acc1[nf], 0, 0, 0); \
        }                                                                     \
    } while (0)

    LOADB(SB0, 0); LOADB(SB1, 1);
    MF1(SB0, 0); LOADB(SB0, 2);
    MF1(SB1, 1); LOADB(SB1, 3);
    MF1(SB0, 2); LOADB(SB0, 4);
    MF1(SB1, 3); LOADB(SB1, 5);
    MF1(SB0, 4); LOADB(SB0, 6);
    MF1(SB1, 5); LOADB(SB1, 7);
    MF1(SB0, 6);
    MF1(SB1, 7);

    // epilogue: + bias, pack bf16, store coalesced in frag layout
    uint2* outp = (uint2*)xz2;
    const size_t cb = (((size_t)t * 64 + rb) * 8 + w) * 16;
#pragma unroll
    for (int m = 0; m < 2; ++m) {
#pragma unroll
        for (int nf = 0; nf < 8; ++nf) {
            f32x4 a = m ? acc1[nf] : acc0[nf];
            float b = bcol[nf];
            uint2 o = {pack2bf(a[0] + b, a[1] + b), pack2bf(a[2] + b, a[3] + b)};
            outp[(cb + m * 8 + nf) * 64 + lane] = o;
        }
    }
#undef LOADB
#undef MF1
}

// -------- phase 2: persistent recurrence, 128 blocks x 16 rows ------------
__global__ __launch_bounds__(512, 2) void lstm_rec(
    const ushort_t* __restrict__ U2, const ushort_t* __restrict__ xz2,
    float* __restrict__ outp, int T) {
    __shared__ __align__(16) ushort_t BL[65536];    // U kf3,kf4 (128 KB)
    __shared__ __align__(16) ushort_t hb[16 * 256]; // h, swizzled (8 KB)

    const int tid = threadIdx.x;
    const int rb = blockIdx.x, row0 = rb * 16;     // rb in [0,128)
    const int w = tid >> 6, lane = tid & 63, r16 = lane & 15, q = lane >> 4;

    // LDS-resident kf3..kf4: linear 128 KB copy from U2 (+192 KB offset)
    {
        const char* srcb = (const char*)U2 + 3 * 65536;
#pragma unroll
        for (int i = 0; i < 16; ++i) {
            int off = i * 8192 + tid * 16;
            __builtin_amdgcn_global_load_lds(
                (const __attribute__((address_space(1))) void*)(srcb + off),
                (__attribute__((address_space(3))) void*)((char*)BL + off),
                16, 0, 0);
        }
    }
    // h0 = 0 (512 threads x 16B = 8 KB)
    *(uint4*)&hb[tid * 8] = (uint4){0, 0, 0, 0};

#define LOADU(BUF, KF_)                                                       \
    _Pragma("unroll") for (int nf = 0; nf < 8; ++nf)                          \
        BUF[nf] = *(const short8*)(U2 +                                       \
            ((((size_t)(KF_) * 8 + w) * 8 + nf) * 64 + lane) * 8);

#define AFRAG(KF_)                                                            \
    (*(const short8*)&hb[r16 * 256 + (((KF_)*4 + q) ^ (r16 & 7)) * 8])

#define MF8(AV_, BARR_)                                                       \
    do {                                                                      \
        short8 a_ = (AV_);                                                    \
        _Pragma("unroll") for (int nf = 0; nf < 8; ++nf)                      \
            acc[nf] = __builtin_amdgcn_mfma_f32_16x16x32_bf16(                \
                a_, (BARR_)[nf], acc[nf], 0, 0, 0);                           \
    } while (0)

#define MF8L(AV_, SEL_)                                                       \
    do {                                                                      \
        short8 a_ = (AV_);                                                    \
        _Pragma("unroll") for (int nf = 0; nf < 8; ++nf) {                    \
            short8 b_ = *(const short8*)&BL[((((SEL_)*8 + w)*8) + nf)*512 + lane*8]; \
            acc[nf] = __builtin_amdgcn_mfma_f32_16x16x32_bf16(                \
                a_, b_, acc[nf], 0, 0, 0);                                    \
        }                                                                     \
    } while (0)

    // register-resident kf0-2 (96 VGPR)
    short8 BR0[8], BR1[8], BR2[8];
    LOADU(BR0, 0); LOADU(BR1, 1); LOADU(BR2, 2);

    short8 SBa[8], SBb[8];
    LOADU(SBa, 5);                       // kf5 for t=0

    const uint2* xzp = (const uint2*)xz2;
    // xz frag base for (t, this block, this wave):
    //   cb(t) = ((t*64 + (rb>>1))*8 + w)*16 + (rb&1)*8
    const size_t cbconst = (((size_t)(rb >> 1)) * 8 + w) * 16 + (size_t)(rb & 1) * 8;
    uint2 XZ[8];
#pragma unroll
    for (int k = 0; k < 8; ++k) XZ[k] = xzp[(cbconst + k) * 64 + lane];

    f32x4 acc[8];
    f32x4 creg[2];
    creg[0] = (f32x4){0.f, 0.f, 0.f, 0.f};
    creg[1] = (f32x4){0.f, 0.f, 0.f, 0.f};

    __syncthreads();   // BL + hb ready

#pragma clang loop unroll(disable)
    for (int t = 0; t < T; ++t) {
#pragma unroll
        for (int nf = 0; nf < 8; ++nf) acc[nf] = (f32x4){0.f, 0.f, 0.f, 0.f};

        LOADU(SBb, 6);                   // kf6 in flight across kf0-4 compute
        MF8(AFRAG(0), BR0);
        MF8(AFRAG(1), BR1);
        MF8(AFRAG(2), BR2);
        MF8L(AFRAG(3), 0);
        MF8L(AFRAG(4), 1);
        MF8(AFRAG(5), SBa);              // kf5
        LOADU(SBa, 7);                   // kf7 in flight across kf6 compute
        MF8(AFRAG(6), SBb);              // kf6
        MF8(AFRAG(7), SBa);              // kf7

        __syncthreads();                 // all hb reads done

        LOADU(SBa, 5);                   // next step's kf5: flies over epilogue

        // epilogue: gates, cell update, h -> swizzled LDS
#pragma unroll
        for (int hf = 0; hf < 2; ++hf) {
#pragma unroll
            for (int j = 0; j < 4; ++j) {
                float zi = acc[0 + hf][j] + xz_at(XZ[0 + hf], j);
                float zf = acc[2 + hf][j] + xz_at(XZ[2 + hf], j);
                float zg = acc[4 + hf][j] + xz_at(XZ[4 + hf], j);
                float zo = acc[6 + hf][j] + xz_at(XZ[6 + hf], j);
                float ig = sigm(zi);
                float fg = sigm(zf);
                float gg = tanh_f(zg);
                float og = sigm(zo);
                float cn = fg * creg[hf][j] + ig * gg;
                float hn = og * tanh_f(cn);
                creg[hf][j] = cn;
                int row = q * 4 + j;
                int hcol = w * 32 + hf * 16 + r16;
                int chunk = (hcol >> 3) ^ (row & 7);
                hb[row * 256 + chunk * 8 + (hcol & 7)] = f2bf(hn);
            }
        }

        // next step's xz: issued here, lands during next MFMA phase.
        // (t=T-1 reads one tile past the 210MB xz region -- still inside the
        //  400MiB workspace, values never used.)
        {
            const size_t cbn = (size_t)(t + 1) * (64 * 8 * 16) + cbconst;
#pragma unroll
            for (int k = 0; k < 8; ++k) XZ[k] = xzp[(cbn + k) * 64 + lane];
        }

        __syncthreads();                 // h visible for next step
    }

    // final output: h from LDS (bf16-rounded, same as recurrence used), c exact
#pragma unroll
    for (int hf = 0; hf < 2; ++hf) {
#pragma unroll
        for (int j = 0; j < 4; ++j) {
            int row = q * 4 + j;
            int hcol = w * 32 + hf * 16 + r16;
            int chunk = (hcol >> 3) ^ (row & 7);
            float hn = bf2f(hb[row * 256 + chunk * 8 + (hcol & 7)]);
            size_t oi = (size_t)(row0 + row) * H_ + hcol;
            outp[oi] = hn;
            outp[(size_t)B_ * H_ + oi] = creg[hf][j];
        }
    }
#undef LOADU
#undef AFRAG
#undef MF8
#undef MF8L
}

extern "C" void kernel_launch(void* const* d_in, const int* in_sizes, int n_in,
                              void* d_out, int out_size, void* d_ws, size_t ws_size,
                              hipStream_t stream) {
    const float* x    = (const float*)d_in[0];
    const float* Wm   = (const float*)d_in[1];
    const float* Um   = (const float*)d_in[2];
    const float* bias = (const float*)d_in[3];

    // ws: W2 (512 KB) | U2 (512 KB) | xz2 (210 MB)   (ws_size = 400 MiB)
    ushort_t* W2  = (ushort_t*)d_ws;
    ushort_t* U2  = W2 + 262144;
    ushort_t* xz2 = U2 + 262144;

    pack_wu<<<256, 256, 0, stream>>>(Wm, Um, W2, U2);
    dim3 g1(T_, 64);
    xw_gemm<<<g1, 512, 0, stream>>>(x, bias, W2, xz2);
    lstm_rec<<<128, 512, 0, stream>>>(U2, xz2, (float*)d_out, T_);
}